// Round 2
// baseline (745.745 us; speedup 1.0000x reference)
//
#include <hip/hip_runtime.h>
#include <hip/hip_bf16.h>

#define DI __device__ __forceinline__

DI float lrelu(float x, float s){ return x > 0.f ? x : s*x; }
DI float gelu_exact(float x){ return 0.5f*x*(1.f + erff(x*0.70710678118654752f)); }

constexpr int NNODE = 50;
constexpr int F0 = 64;     // d_state
constexpr int NT = 512;    // threads per block

// LDS float-offset map (total 24768 floats = 96.75 KB)
//  xs   [50][68]   @ 0      (dead after phase 3)
//  xh1  [50][260]  @ 3584   (dead after phase 5)   } hA [50][132] @ 0, hB [50][132] @ 6656 overlay later
//  xh2  [50][132]  @ 16640
//  wes1 [2][2][64] @ 23296
//  wes2 [2][256]   @ 23552
//  es1  [50][2]    @ 24064 ; ed1 @ 24164 ; es2 @ 24264 ; ed2 @ 24314
//  geb  [128]      @ 24368 ; vh1 @ 24496 ; vh2 @ 24624 ; red @ 24752

__global__ __launch_bounds__(NT)
void ac_fused(const float* __restrict__ state,
  const float* __restrict__ w1,  const float* __restrict__ as1, const float* __restrict__ ad1, const float* __restrict__ b1,
  const float* __restrict__ w2,  const float* __restrict__ as2, const float* __restrict__ ad2, const float* __restrict__ b2,
  const float* __restrict__ aw1, const float* __restrict__ ab1,
  const float* __restrict__ aw2, const float* __restrict__ ab2,
  const float* __restrict__ aw3, const float* __restrict__ ab3,
  const float* __restrict__ vw1, const float* __restrict__ vb1,
  const float* __restrict__ vw2, const float* __restrict__ vb2,
  const float* __restrict__ vw3, const float* __restrict__ vb3,
  float* __restrict__ out_mean, float* __restrict__ out_val)
{
  __shared__ __align__(16) float sm[24768];
  float* xs   = sm;
  float* xh1  = sm + 3584;
  float* xh2  = sm + 16640;
  float* wes1 = sm + 23296;
  float* wes2 = sm + 23552;
  float* es1  = sm + 24064;
  float* ed1  = sm + 24164;
  float* es2  = sm + 24264;
  float* ed2  = sm + 24314;
  float* geb  = sm + 24368;
  float* vh1  = sm + 24496;
  float* vh2  = sm + 24624;
  float* red  = sm + 24752;
  float* hA   = sm;          // overlay (xs+xh1 region, dead by then)
  float* hB   = sm + 6656;

  const int tid = threadIdx.x;
  const int b   = blockIdx.x;

  // ---- phase 1: load state -> xs (f32, padded stride 68) ----
  {
    const float* xb = state + (size_t)b * (NNODE*F0);
    for (int t = tid; t < NNODE*F0; t += NT){
      int i = t >> 6, k = t & 63;
      xs[i*68 + k] = xb[t];
    }
  }
  __syncthreads();

  // ---- phase 2: GEMM1  xh1[i][j] = xs[i][:] . W1[:,j]  ;  wes1 = W1 folded with att vecs ----
  {
    const int j = tid & 255, p = tid >> 8;
    float wcol[64];
    #pragma unroll
    for (int k=0;k<64;++k) wcol[k] = w1[k*256 + j];
    for (int ii=0; ii<25; ++ii){
      const int i = 2*ii + p;
      const float* xr = xs + i*68;
      float a0=0.f,a1=0.f,a2=0.f,a3=0.f;
      #pragma unroll
      for (int k=0;k<64;k+=4){
        a0 += xr[k  ]*wcol[k  ]; a1 += xr[k+1]*wcol[k+1];
        a2 += xr[k+2]*wcol[k+2]; a3 += xr[k+3]*wcol[k+3];
      }
      xh1[i*260 + j] = (a0+a1)+(a2+a3);
    }
    if (tid < 256){
      const int sd = tid >> 7, r = tid & 127, h = r >> 6, k = r & 63;
      const float* av = (sd ? ad1 : as1) + h*128;
      const float* wr = w1 + k*256 + h*128;
      float s = 0.f;
      for (int c=0;c<128;++c) s += wr[c] * av[c];
      wes1[sd*128 + h*64 + k] = s;
    }
  }
  __syncthreads();

  // ---- phase 3: es1/ed1[i][h] = xs[i][:] . wes1[sd][h][:] ----
  if (tid < 200){
    const int i = tid >> 2, h = (tid>>1)&1, sd = tid&1;
    const float* wv = wes1 + sd*128 + h*64;
    const float* xr = xs + i*68;
    float a0=0.f,a1=0.f;
    #pragma unroll
    for (int k=0;k<64;k+=2){ a0 += xr[k]*wv[k]; a1 += xr[k+1]*wv[k+1]; }
    (sd ? ed1 : es1)[i*2 + h] = a0+a1;
  }
  __syncthreads();

  // ---- phase 4: attention1 (3-pt stencil softmax) in-place + bias + GELU ; wes2 ----
  if (tid < 256){
    const int j = tid, h = j >> 7;
    const float bj = b1[j];
    float prev = 0.f;
    for (int i=0;i<NNODE;++i){
      const float cur = xh1[i*260 + j];
      const float nxt = (i<NNODE-1) ? xh1[(i+1)*260 + j] : 0.f;
      const float edi = ed1[i*2+h];
      const float esf = lrelu(es1[i*2+h] + edi, 0.2f);
      float m = esf, el = 0.f, er = 0.f;
      if (i>0)       { el = lrelu(es1[(i-1)*2+h] + edi, 0.2f); m = fmaxf(m, el); }
      if (i<NNODE-1) { er = lrelu(es1[(i+1)*2+h] + edi, 0.2f); m = fmaxf(m, er); }
      const float wsf = __expf(esf - m);
      const float wlf = (i>0)       ? __expf(el - m) : 0.f;
      const float wrf = (i<NNODE-1) ? __expf(er - m) : 0.f;
      const float agg = (wlf*prev + wsf*cur + wrf*nxt) / (wlf+wsf+wrf);
      xh1[i*260 + j] = gelu_exact(agg + bj);
      prev = cur;
    }
  }
  {
    const int sd = tid >> 8, k = tid & 255;
    const float* av = sd ? ad2 : as2;
    const float* wr = w2 + k*128;
    float s = 0.f;
    for (int c=0;c<128;++c) s += wr[c] * av[c];
    wes2[sd*256 + k] = s;
  }
  __syncthreads();

  // ---- phase 5: GEMM2  xh2 = out1 @ W2 ; es2/ed2 ----
  {
    const int j = tid & 127, q = tid >> 7;
    float acc[13];
    #pragma unroll
    for (int ii=0;ii<13;++ii) acc[ii]=0.f;
    for (int kc=0;kc<4;++kc){
      float wc[64];
      #pragma unroll
      for (int kk=0;kk<64;++kk) wc[kk] = w2[(kc*64+kk)*128 + j];
      #pragma unroll
      for (int ii=0;ii<13;++ii){
        int i = q*13 + ii; if (i > NNODE-1) i = NNODE-1;
        const float* xr = xh1 + i*260 + kc*64;
        float a0=0.f,a1=0.f,a2=0.f,a3=0.f;
        #pragma unroll
        for (int kk=0;kk<64;kk+=4){
          a0 += xr[kk  ]*wc[kk  ]; a1 += xr[kk+1]*wc[kk+1];
          a2 += xr[kk+2]*wc[kk+2]; a3 += xr[kk+3]*wc[kk+3];
        }
        acc[ii] += (a0+a1)+(a2+a3);
      }
    }
    #pragma unroll
    for (int ii=0;ii<13;++ii){
      const int i = q*13 + ii;
      if (i < NNODE) xh2[i*132 + j] = acc[ii];
    }
  }
  if (tid < 100){
    const int i = tid >> 1, sd = tid & 1;
    const float* wv = wes2 + sd*256;
    const float* xr = xh1 + i*260;
    float a0=0.f,a1=0.f;
    #pragma unroll
    for (int k=0;k<256;k+=2){ a0 += xr[k]*wv[k]; a1 += xr[k+1]*wv[k+1]; }
    (sd ? ed2 : es2)[i] = a0+a1;
  }
  __syncthreads();

  // ---- phase 6: attention2 in-place + bias + GELU  (x2 lives in xh2) ----
  if (tid < 128){
    const int j = tid;
    const float bj = b2[j];
    float prev = 0.f;
    for (int i=0;i<NNODE;++i){
      const float cur = xh2[i*132 + j];
      const float nxt = (i<NNODE-1) ? xh2[(i+1)*132 + j] : 0.f;
      const float edi = ed2[i];
      const float esf = lrelu(es2[i] + edi, 0.2f);
      float m = esf, el = 0.f, er = 0.f;
      if (i>0)       { el = lrelu(es2[i-1] + edi, 0.2f); m = fmaxf(m, el); }
      if (i<NNODE-1) { er = lrelu(es2[i+1] + edi, 0.2f); m = fmaxf(m, er); }
      const float wsf = __expf(esf - m);
      const float wlf = (i>0)       ? __expf(el - m) : 0.f;
      const float wrf = (i<NNODE-1) ? __expf(er - m) : 0.f;
      const float agg = (wlf*prev + wsf*cur + wrf*nxt) / (wlf+wsf+wrf);
      xh2[i*132 + j] = gelu_exact(agg + bj);
      prev = cur;
    }
  }
  __syncthreads();

  // ---- phase 7: actor L1 (x2 @ aw1 +ab1, lrelu .01) -> hA ; mean-pool -> geb ----
  {
    const int j = tid & 127, q = tid >> 7;
    float acc[13];
    #pragma unroll
    for (int ii=0;ii<13;++ii) acc[ii]=0.f;
    for (int kc=0;kc<2;++kc){
      float wc[64];
      #pragma unroll
      for (int kk=0;kk<64;++kk) wc[kk] = aw1[(kc*64+kk)*128 + j];
      #pragma unroll
      for (int ii=0;ii<13;++ii){
        int i = q*13 + ii; if (i > NNODE-1) i = NNODE-1;
        const float* xr = xh2 + i*132 + kc*64;
        float a0=0.f,a1=0.f,a2=0.f,a3=0.f;
        #pragma unroll
        for (int kk=0;kk<64;kk+=4){
          a0 += xr[kk  ]*wc[kk  ]; a1 += xr[kk+1]*wc[kk+1];
          a2 += xr[kk+2]*wc[kk+2]; a3 += xr[kk+3]*wc[kk+3];
        }
        acc[ii] += (a0+a1)+(a2+a3);
      }
    }
    const float bj = ab1[tid & 127];
    #pragma unroll
    for (int ii=0;ii<13;++ii){
      const int i = q*13 + ii;
      if (i < NNODE) hA[i*132 + j] = lrelu(acc[ii] + bj, 0.01f);
    }
  }
  if (tid < 128){
    float s = 0.f;
    for (int i=0;i<NNODE;++i) s += xh2[i*132 + tid];
    geb[tid] = s * (1.f/NNODE);
  }
  __syncthreads();

  // ---- phase 8: actor L2 -> hB ; value L1 -> vh1 ----
  {
    const int j = tid & 127, q = tid >> 7;
    float acc[13];
    #pragma unroll
    for (int ii=0;ii<13;++ii) acc[ii]=0.f;
    for (int kc=0;kc<2;++kc){
      float wc[64];
      #pragma unroll
      for (int kk=0;kk<64;++kk) wc[kk] = aw2[(kc*64+kk)*128 + j];
      #pragma unroll
      for (int ii=0;ii<13;++ii){
        int i = q*13 + ii; if (i > NNODE-1) i = NNODE-1;
        const float* xr = hA + i*132 + kc*64;
        float a0=0.f,a1=0.f,a2=0.f,a3=0.f;
        #pragma unroll
        for (int kk=0;kk<64;kk+=4){
          a0 += xr[kk  ]*wc[kk  ]; a1 += xr[kk+1]*wc[kk+1];
          a2 += xr[kk+2]*wc[kk+2]; a3 += xr[kk+3]*wc[kk+3];
        }
        acc[ii] += (a0+a1)+(a2+a3);
      }
    }
    const float bj = ab2[tid & 127];
    #pragma unroll
    for (int ii=0;ii<13;++ii){
      const int i = q*13 + ii;
      if (i < NNODE) hB[i*132 + j] = lrelu(acc[ii] + bj, 0.01f);
    }
  }
  if (tid < 128){
    const int j = tid;
    float a0=0.f,a1=0.f;
    #pragma unroll
    for (int k=0;k<128;k+=2){
      a0 += geb[k  ]*vw1[(k  )*128+j];
      a1 += geb[k+1]*vw1[(k+1)*128+j];
    }
    vh1[j] = lrelu(a0+a1 + vb1[j], 0.01f);
  }
  __syncthreads();

  // ---- phase 9: actor L3 -> out_mean ; value L2 -> vh2 ----
  if (tid < 200){
    const int i = tid >> 2, m = tid & 3;
    const float* xr = hB + i*132;
    float a0=0.f,a1=0.f,a2=0.f,a3=0.f;
    #pragma unroll
    for (int k=0;k<128;k+=4){
      a0 += xr[k  ]*aw3[(k  )*4+m]; a1 += xr[k+1]*aw3[(k+1)*4+m];
      a2 += xr[k+2]*aw3[(k+2)*4+m]; a3 += xr[k+3]*aw3[(k+3)*4+m];
    }
    out_mean[(size_t)b*200 + i*4 + m] = (a0+a1)+(a2+a3) + ab3[m];
  }
  if (tid >= 256 && tid < 384){
    const int j = tid - 256;
    float a0=0.f,a1=0.f;
    #pragma unroll
    for (int k=0;k<128;k+=2){
      a0 += vh1[k  ]*vw2[(k  )*128+j];
      a1 += vh1[k+1]*vw2[(k+1)*128+j];
    }
    vh2[j] = lrelu(a0+a1 + vb2[j], 0.01f);
  }
  __syncthreads();

  // ---- phase 10: value head reduce + write ----
  if (tid < 128){
    float p = vh2[tid] * vw3[tid];
    #pragma unroll
    for (int off=32; off>0; off>>=1) p += __shfl_down(p, off);
    if ((tid & 63) == 0) red[tid>>6] = p;
  }
  __syncthreads();
  if (tid == 0) out_val[b] = red[0] + red[1] + vb3[0];
}

extern "C" void kernel_launch(void* const* d_in, const int* in_sizes, int n_in,
                              void* d_out, int out_size, void* d_ws, size_t ws_size,
                              hipStream_t stream)
{
  const float* state = (const float*)d_in[0];
  const float* w1    = (const float*)d_in[1];
  const float* as1   = (const float*)d_in[2];
  const float* ad1   = (const float*)d_in[3];
  const float* b1_   = (const float*)d_in[4];
  const float* w2    = (const float*)d_in[5];
  const float* as2   = (const float*)d_in[6];
  const float* ad2   = (const float*)d_in[7];
  const float* b2_   = (const float*)d_in[8];
  const float* aw1   = (const float*)d_in[9];
  const float* ab1   = (const float*)d_in[10];
  const float* aw2   = (const float*)d_in[11];
  const float* ab2   = (const float*)d_in[12];
  const float* aw3   = (const float*)d_in[13];
  const float* ab3   = (const float*)d_in[14];
  const float* vw1   = (const float*)d_in[15];
  const float* vb1   = (const float*)d_in[16];
  const float* vw2   = (const float*)d_in[17];
  const float* vb2   = (const float*)d_in[18];
  const float* vw3   = (const float*)d_in[19];
  const float* vb3   = (const float*)d_in[20];

  const int B = in_sizes[0] / (NNODE * F0);   // 2048
  float* out_mean = (float*)d_out;
  float* out_val  = out_mean + (size_t)B * 200;

  ac_fused<<<B, NT, 0, stream>>>(state,
      w1, as1, ad1, b1_, w2, as2, ad2, b2_,
      aw1, ab1, aw2, ab2, aw3, ab3,
      vw1, vb1, vw2, vb2, vw3, vb3,
      out_mean, out_val);
}

// Round 3
// 261.839 us; speedup vs baseline: 2.8481x; 2.8481x over previous
//
#include <hip/hip_runtime.h>

#define DI __device__ __forceinline__

typedef unsigned int uint32;
typedef unsigned short u16;
typedef __attribute__((ext_vector_type(8))) short s8v;   // 8 bf16 (4 VGPR)
typedef __attribute__((ext_vector_type(4))) float f4v;   // MFMA accumulator

DI float lrelu(float x, float s){ return x > 0.f ? x : s*x; }
DI float gelu_exact(float x){ return 0.5f*x*(1.f + erff(x*0.70710678118654752f)); }
DI u16 f2bu(float f){ uint32 u = __float_as_uint(f); return (u16)((u + 0x7FFFu + ((u>>16)&1u)) >> 16); }

DI f4v mfma16(s8v a, s8v b, f4v c){
  return __builtin_amdgcn_mfma_f32_16x16x32_bf16(a, b, c, 0, 0, 0);
}

constexpr int NNODE = 50;
constexpr int NT = 512;
constexpr int SCS = 266;     // sc row stride (f32) — conflict-free for C writes & column reads

// d_ws layout (u16 units):
constexpr int WS1  = 0;       // W1x^T  [272][64]  (cols 256..259 = es1h0,es1h1,ed1h0,ed1h1; 260+ zero)
constexpr int WS2  = 17408;   // W2x^T  [144][256] (col 128 = es2, 129 = ed2; 130+ zero)
constexpr int WSA1 = 54272;   // aw1^T  [128][128]
constexpr int WSA2 = 70656;   // aw2^T  [128][128]
constexpr int WSTOT= 87040;   // * 2 bytes = 174,080 B

__global__ __launch_bounds__(256)
void ac_prep(const float* __restrict__ w1, const float* __restrict__ as1, const float* __restrict__ ad1,
             const float* __restrict__ w2, const float* __restrict__ as2, const float* __restrict__ ad2,
             const float* __restrict__ aw1, const float* __restrict__ aw2, u16* __restrict__ ws)
{
  const int T1 = 272*64, T2 = 144*256, T3 = 128*128;
  for (int t = blockIdx.x*blockDim.x + threadIdx.x; t < WSTOT; t += gridDim.x*blockDim.x){
    float v; int o;
    if (t < T1){
      int n = t>>6, k = t&63;
      if (n < 256) v = w1[k*256 + n];
      else if (n < 260){
        int h = (n-256)&1, sd = (n-256)>>1;
        const float* av = (sd ? ad1 : as1) + h*128;
        const float* wr = w1 + k*256 + h*128;
        float s = 0.f;
        for (int c=0;c<128;++c) s += wr[c]*av[c];
        v = s;
      } else v = 0.f;
      o = WS1 + n*64 + k;
    } else if (t < T1+T2){
      int j = t - T1, n = j>>8, k = j&255;
      if (n < 128) v = w2[k*128 + n];
      else if (n < 130){
        const float* av = (n==129) ? ad2 : as2;
        const float* wr = w2 + k*128;
        float s = 0.f;
        for (int c=0;c<128;++c) s += wr[c]*av[c];
        v = s;
      } else v = 0.f;
      o = WS2 + n*256 + k;
    } else if (t < T1+T2+T3){
      int j = t - T1 - T2, n = j>>7, k = j&127;
      v = aw1[k*128 + n];
      o = WSA1 + n*128 + k;
    } else {
      int j = t - T1 - T2 - T3, n = j>>7, k = j&127;
      v = aw2[k*128 + n];
      o = WSA2 + n*128 + k;
    }
    ws[o] = f2bu(v);
  }
}

// LDS map (f32 offsets), total 27912 f = 111.6 KB:
//  sc   [64][266] f32 @ 0        (C of every GEMM + es score cols)
//  Abuf bf16 (16384 u16 = 8192f) @ 17024   (A2 [64][256] / A3,A4 [64][128], XOR-swizzled)
//  As   bf16 (4096 u16 = 2048f)  @ 25216   (state tile [64][64], XOR-swizzled)
//  geb2 [2][128] @ 27264 ; geb [128] @ 27520 ; vh1 @ 27648 ; vh2 @ 27776 ; red @ 27904

__global__ __launch_bounds__(NT)
void ac_main(const float* __restrict__ state,
             const float* __restrict__ b1, const float* __restrict__ b2,
             const float* __restrict__ ab1, const float* __restrict__ ab2,
             const float* __restrict__ aw3, const float* __restrict__ ab3,
             const float* __restrict__ vw1, const float* __restrict__ vb1,
             const float* __restrict__ vw2, const float* __restrict__ vb2,
             const float* __restrict__ vw3, const float* __restrict__ vb3,
             const u16* __restrict__ ws,
             float* __restrict__ out_mean, float* __restrict__ out_val)
{
  __shared__ __align__(16) float sm[27912];
  float* sc   = sm;
  u16*   pAb  = (u16*)(sm + 17024);
  u16*   pAs  = (u16*)(sm + 25216);
  float* geb2 = sm + 27264;
  float* geb  = sm + 27520;
  float* vh1  = sm + 27648;
  float* vh2  = sm + 27776;
  float* red  = sm + 27904;

  const int tid = threadIdx.x, b = blockIdx.x;
  const int wid = tid>>6, l15 = tid&15, g = (tid>>4)&3;

  // ---- P0: pack state -> As bf16 [64][64], XOR-swizzled, rows 50..63 zero ----
  {
    const float* xb = state + (size_t)b * (NNODE*64);
    for (int t = tid; t < 4096; t += NT){
      int i = t>>6, k = t&63;
      float v = (i < NNODE) ? xb[i*64 + k] : 0.f;
      pAs[i*64 + (k ^ ((i&7)<<3))] = f2bu(v);
    }
  }
  __syncthreads();

  // ---- P1: G1  C[64][260] = As[64x64] x W1x^T   (cols 256..259 = es/ed scores) ----
  {
    s8v a[4][2];
    #pragma unroll
    for (int mt=0;mt<4;++mt)
      #pragma unroll
      for (int ks=0;ks<2;++ks){
        int row = mt*16 + l15, c = ks*32 + g*8;
        a[mt][ks] = *(const s8v*)(pAs + row*64 + (c ^ ((row&7)<<3)));
      }
    for (int nt = wid; nt < 17; nt += 8){
      f4v acc[4];
      #pragma unroll
      for (int mt=0;mt<4;++mt) acc[mt] = (f4v){0.f,0.f,0.f,0.f};
      #pragma unroll
      for (int ks=0;ks<2;++ks){
        s8v bf = *(const s8v*)(ws + WS1 + (nt*16 + l15)*64 + ks*32 + g*8);
        #pragma unroll
        for (int mt=0;mt<4;++mt) acc[mt] = mfma16(a[mt][ks], bf, acc[mt]);
      }
      const int col = nt*16 + l15;
      if (col < 260){
        #pragma unroll
        for (int mt=0;mt<4;++mt){
          const int r0 = mt*16 + g*4;
          #pragma unroll
          for (int r=0;r<4;++r) sc[(r0+r)*SCS + col] = acc[mt][r];
        }
      }
    }
  }
  __syncthreads();

  // ---- P2: attention1 (3-pt stencil softmax) + bias + GELU -> A2 bf16 [64][256] ----
  {
    const int q = tid>>8, j = tid&255, h = j>>7;
    const float bj = b1[j];
    const int i0 = q*25;
    float prev = (i0 > 0) ? sc[(i0-1)*SCS + j] : 0.f;
    for (int i = i0; i < i0+25; ++i){
      const float cur = sc[i*SCS + j];
      const float nxt = (i < NNODE-1) ? sc[(i+1)*SCS + j] : 0.f;
      const float edi = sc[i*SCS + 258 + h];
      const float esf = lrelu(sc[i*SCS + 256 + h] + edi, 0.2f);
      float m = esf, el = 0.f, er = 0.f;
      if (i > 0)       { el = lrelu(sc[(i-1)*SCS + 256 + h] + edi, 0.2f); m = fmaxf(m, el); }
      if (i < NNODE-1) { er = lrelu(sc[(i+1)*SCS + 256 + h] + edi, 0.2f); m = fmaxf(m, er); }
      const float wS = __expf(esf - m);
      const float wL = (i > 0)       ? __expf(el - m) : 0.f;
      const float wR = (i < NNODE-1) ? __expf(er - m) : 0.f;
      const float agg = (wL*prev + wS*cur + wR*nxt) / (wL+wS+wR);
      const float v = gelu_exact(agg + bj);
      pAb[i*256 + (j ^ ((i&7)<<3))] = f2bu(v);
      prev = cur;
    }
  }
  __syncthreads();

  // ---- P3: G2  C[64][130] = A2[64x256] x W2x^T  (cols 128,129 = es2,ed2) ----
  for (int nt = wid; nt < 9; nt += 8){
    f4v acc[4];
    #pragma unroll
    for (int mt=0;mt<4;++mt) acc[mt] = (f4v){0.f,0.f,0.f,0.f};
    #pragma unroll
    for (int ks=0;ks<8;++ks){
      s8v bf = *(const s8v*)(ws + WS2 + (nt*16 + l15)*256 + ks*32 + g*8);
      #pragma unroll
      for (int mt=0;mt<4;++mt){
        const int row = mt*16 + l15, c = ks*32 + g*8;
        s8v a = *(const s8v*)(pAb + row*256 + (c ^ ((row&7)<<3)));
        acc[mt] = mfma16(a, bf, acc[mt]);
      }
    }
    const int col = nt*16 + l15;
    if (col < 130){
      #pragma unroll
      for (int mt=0;mt<4;++mt){
        const int r0 = mt*16 + g*4;
        #pragma unroll
        for (int r=0;r<4;++r) sc[(r0+r)*SCS + col] = acc[mt][r];
      }
    }
  }
  __syncthreads();

  // ---- P4: attention2 + bias + GELU -> A3 bf16 [64][128] ; pool partials ----
  if (tid < 256){
    const int q = tid>>7, j = tid&127;
    const float bj = b2[j];
    const int i0 = q*25;
    float prev = (i0 > 0) ? sc[(i0-1)*SCS + j] : 0.f;
    float ps = 0.f;
    for (int i = i0; i < i0+25; ++i){
      const float cur = sc[i*SCS + j];
      const float nxt = (i < NNODE-1) ? sc[(i+1)*SCS + j] : 0.f;
      const float edi = sc[i*SCS + 129];
      const float esf = lrelu(sc[i*SCS + 128] + edi, 0.2f);
      float m = esf, el = 0.f, er = 0.f;
      if (i > 0)       { el = lrelu(sc[(i-1)*SCS + 128] + edi, 0.2f); m = fmaxf(m, el); }
      if (i < NNODE-1) { er = lrelu(sc[(i+1)*SCS + 128] + edi, 0.2f); m = fmaxf(m, er); }
      const float wS = __expf(esf - m);
      const float wL = (i > 0)       ? __expf(el - m) : 0.f;
      const float wR = (i < NNODE-1) ? __expf(er - m) : 0.f;
      const float agg = (wL*prev + wS*cur + wR*nxt) / (wL+wS+wR);
      const float v = gelu_exact(agg + bj);
      pAb[i*128 + (j ^ ((i&7)<<3))] = f2bu(v);
      ps += v;
      prev = cur;
    }
    geb2[q*128 + j] = ps;
  }
  __syncthreads();

  // ---- P5: G3  C[64][128] = A3 x aw1^T ----
  {
    const int nt = wid;
    f4v acc[4];
    #pragma unroll
    for (int mt=0;mt<4;++mt) acc[mt] = (f4v){0.f,0.f,0.f,0.f};
    #pragma unroll
    for (int ks=0;ks<4;++ks){
      s8v bf = *(const s8v*)(ws + WSA1 + (nt*16 + l15)*128 + ks*32 + g*8);
      #pragma unroll
      for (int mt=0;mt<4;++mt){
        const int row = mt*16 + l15, c = ks*32 + g*8;
        s8v a = *(const s8v*)(pAb + row*128 + (c ^ ((row&7)<<3)));
        acc[mt] = mfma16(a, bf, acc[mt]);
      }
    }
    const int col = nt*16 + l15;
    #pragma unroll
    for (int mt=0;mt<4;++mt){
      const int r0 = mt*16 + g*4;
      #pragma unroll
      for (int r=0;r<4;++r) sc[(r0+r)*SCS + col] = acc[mt][r];
    }
  }
  __syncthreads();

  // ---- P6: lrelu(C3+ab1) -> A4 bf16 ; finalize pooled graph emb ----
  if (tid < 256){
    const int q = tid>>7, j = tid&127;
    const float bj = ab1[j];
    for (int i = q*25; i < q*25+25; ++i){
      const float v = lrelu(sc[i*SCS + j] + bj, 0.01f);
      pAb[i*128 + (j ^ ((i&7)<<3))] = f2bu(v);
    }
  } else if (tid < 384){
    const int j = tid - 256;
    geb[j] = (geb2[j] + geb2[128 + j]) * 0.02f;   // 1/50
  }
  __syncthreads();

  // ---- P7: G4  C[64][128] = A4 x aw2^T ----
  {
    const int nt = wid;
    f4v acc[4];
    #pragma unroll
    for (int mt=0;mt<4;++mt) acc[mt] = (f4v){0.f,0.f,0.f,0.f};
    #pragma unroll
    for (int ks=0;ks<4;++ks){
      s8v bf = *(const s8v*)(ws + WSA2 + (nt*16 + l15)*128 + ks*32 + g*8);
      #pragma unroll
      for (int mt=0;mt<4;++mt){
        const int row = mt*16 + l15, c = ks*32 + g*8;
        s8v a = *(const s8v*)(pAb + row*128 + (c ^ ((row&7)<<3)));
        acc[mt] = mfma16(a, bf, acc[mt]);
      }
    }
    const int col = nt*16 + l15;
    #pragma unroll
    for (int mt=0;mt<4;++mt){
      const int r0 = mt*16 + g*4;
      #pragma unroll
      for (int r=0;r<4;++r) sc[(r0+r)*SCS + col] = acc[mt][r];
    }
  }
  __syncthreads();

  // ---- P8: actor L3 (lrelu(C4+ab2) @ aw3 + ab3) -> out_mean ; value L1 -> vh1 ----
  if (tid < 200){
    const int i = tid>>2, m = tid&3;
    const float* scr = sc + i*SCS;
    float s = 0.f;
    for (int k=0;k<128;++k) s += lrelu(scr[k] + ab2[k], 0.01f) * aw3[k*4 + m];
    out_mean[(size_t)b*200 + i*4 + m] = s + ab3[m];
  } else if (tid >= 256 && tid < 384){
    const int j = tid - 256;
    float a0=0.f, a1=0.f;
    #pragma unroll
    for (int k=0;k<128;k+=2){
      a0 += geb[k  ]*vw1[(k  )*128 + j];
      a1 += geb[k+1]*vw1[(k+1)*128 + j];
    }
    vh1[j] = lrelu(a0+a1 + vb1[j], 0.01f);
  }
  __syncthreads();

  // ---- P9: value L2 -> vh2 ----
  if (tid < 128){
    const int j = tid;
    float a0=0.f, a1=0.f;
    #pragma unroll
    for (int k=0;k<128;k+=2){
      a0 += vh1[k  ]*vw2[(k  )*128 + j];
      a1 += vh1[k+1]*vw2[(k+1)*128 + j];
    }
    vh2[j] = lrelu(a0+a1 + vb2[j], 0.01f);
  }
  __syncthreads();

  // ---- P10: value head reduce + write ----
  if (tid < 128){
    float p = vh2[tid] * vw3[tid];
    #pragma unroll
    for (int off=32; off>0; off>>=1) p += __shfl_down(p, off);
    if ((tid & 63) == 0) red[tid>>6] = p;
  }
  __syncthreads();
  if (tid == 0) out_val[b] = red[0] + red[1] + vb3[0];
}

extern "C" void kernel_launch(void* const* d_in, const int* in_sizes, int n_in,
                              void* d_out, int out_size, void* d_ws, size_t ws_size,
                              hipStream_t stream)
{
  const float* state = (const float*)d_in[0];
  const float* w1    = (const float*)d_in[1];
  const float* as1   = (const float*)d_in[2];
  const float* ad1   = (const float*)d_in[3];
  const float* b1_   = (const float*)d_in[4];
  const float* w2    = (const float*)d_in[5];
  const float* as2   = (const float*)d_in[6];
  const float* ad2   = (const float*)d_in[7];
  const float* b2_   = (const float*)d_in[8];
  const float* aw1   = (const float*)d_in[9];
  const float* ab1   = (const float*)d_in[10];
  const float* aw2   = (const float*)d_in[11];
  const float* ab2   = (const float*)d_in[12];
  const float* aw3   = (const float*)d_in[13];
  const float* ab3   = (const float*)d_in[14];
  const float* vw1   = (const float*)d_in[15];
  const float* vb1   = (const float*)d_in[16];
  const float* vw2   = (const float*)d_in[17];
  const float* vb2   = (const float*)d_in[18];
  const float* vw3   = (const float*)d_in[19];
  const float* vb3   = (const float*)d_in[20];

  const int B = in_sizes[0] / (NNODE * 64);   // 2048
  float* out_mean = (float*)d_out;
  float* out_val  = out_mean + (size_t)B * 200;
  u16* ws = (u16*)d_ws;

  ac_prep<<<128, 256, 0, stream>>>(w1, as1, ad1, w2, as2, ad2, aw1, aw2, ws);
  ac_main<<<B, NT, 0, stream>>>(state, b1_, b2_, ab1, ab2, aw3, ab3,
                                vw1, vb1, vw2, vb2, vw3, vb3,
                                ws, out_mean, out_val);
}

// Round 4
// 153.323 us; speedup vs baseline: 4.8639x; 1.7078x over previous
//
#include <hip/hip_runtime.h>

#define DI __device__ __forceinline__

typedef unsigned int uint32;
typedef unsigned short u16;
typedef __attribute__((ext_vector_type(8))) short s8v;   // 8 bf16 (4 VGPR)
typedef __attribute__((ext_vector_type(4))) float f4v;   // MFMA accumulator

DI float lrelu(float x, float s){ return x > 0.f ? x : s*x; }
DI u16 f2bu(float f){ uint32 u = __float_as_uint(f); return (u16)((u + 0x7FFFu + ((u>>16)&1u)) >> 16); }
DI float fastrcp(float x){ float r; asm("v_rcp_f32 %0, %1" : "=v"(r) : "v"(x)); return r; }

// branch-free gelu (erf via Abramowitz-Stegun 7.1.26, |eps|<=1.5e-7)
DI float gelu_f(float x){
  const float z = fabsf(x) * 0.70710678118654752f;
  const float t = fastrcp(1.f + 0.3275911f*z);
  float p = 1.061405429f;
  p = p*t - 1.453152027f;
  p = p*t + 1.421413741f;
  p = p*t - 0.284496736f;
  p = p*t + 0.254829592f;
  p = p*t;
  const float e = __expf(-z*z);
  float er = 1.f - p*e;
  er = copysignf(er, x);
  return 0.5f*x*(1.f + er);
}

DI f4v mfma16(s8v a, s8v b, f4v c){
  return __builtin_amdgcn_mfma_f32_16x16x32_bf16(a, b, c, 0, 0, 0);
}

constexpr int NNODE = 50;
constexpr int NT = 512;
constexpr int SCS = 134;     // sc row stride (f32)

// d_ws layout (u16 units):
constexpr int WS1  = 0;       // per-head [144][64]: rows 0..127 = W1^T head h, 128=es fold, 129=ed fold
constexpr int WS2  = 18432;   // [144][256]: rows 0..127 = W2^T, 128=es2 fold, 129=ed2 fold
constexpr int WSA1 = 55296;   // aw1^T [128][128]
constexpr int WSA2 = 71680;   // aw2^T [128][128]
constexpr int WSTOT= 88064;   // * 2 bytes

__global__ __launch_bounds__(256)
void ac_prep(const float* __restrict__ w1, const float* __restrict__ as1, const float* __restrict__ ad1,
             const float* __restrict__ w2, const float* __restrict__ as2, const float* __restrict__ ad2,
             const float* __restrict__ aw1, const float* __restrict__ aw2, u16* __restrict__ ws)
{
  const int T1 = 2*144*64, T2 = 144*256, T3 = 128*128;
  for (int t = blockIdx.x*blockDim.x + threadIdx.x; t < WSTOT; t += gridDim.x*blockDim.x){
    float v; int o;
    if (t < T1){
      int h = t / 9216, r = t - h*9216, n = r>>6, k = r&63;
      if (n < 128) v = w1[k*256 + h*128 + n];
      else if (n < 130){
        const float* av = ((n==129) ? ad1 : as1) + h*128;
        const float* wr = w1 + k*256 + h*128;
        float s = 0.f;
        for (int c=0;c<128;++c) s += wr[c]*av[c];
        v = s;
      } else v = 0.f;
      o = WS1 + h*9216 + n*64 + k;
    } else if (t < T1+T2){
      int j = t - T1, n = j>>8, k = j&255;
      if (n < 128) v = w2[k*128 + n];
      else if (n < 130){
        const float* av = (n==129) ? ad2 : as2;
        const float* wr = w2 + k*128;
        float s = 0.f;
        for (int c=0;c<128;++c) s += wr[c]*av[c];
        v = s;
      } else v = 0.f;
      o = WS2 + n*256 + k;
    } else if (t < T1+T2+T3){
      int j = t - T1 - T2, n = j>>7, k = j&127;
      v = aw1[k*128 + n];
      o = WSA1 + n*128 + k;
    } else {
      int j = t - T1 - T2 - T3, n = j>>7, k = j&127;
      v = aw2[k*128 + n];
      o = WSA2 + n*128 + k;
    }
    ws[o] = f2bu(v);
  }
}

// LDS map (f32 words), total 18816 f = 75.26 KB -> 2 blocks/CU:
//  sc   [64][134] f32 @ 0          (C of every GEMM; score cols at 128/129)
//  Abuf bf16 16384 u16 @ 8576      (A2 [64][256] / A3 [64][128] at 0..8191, A4 [64][128] at 8192..)
//  As   bf16 4096 u16  @ 16768     (state tile [64][64]; dead after G1 -> overlay smalls)
//  geb4 [4][128] @ 16768 ; geb @ 17280 ; vh1 @ 17408

__global__ __launch_bounds__(NT, 4)
void ac_main(const float* __restrict__ state,
             const float* __restrict__ b1, const float* __restrict__ b2,
             const float* __restrict__ ab1, const float* __restrict__ ab2,
             const float* __restrict__ aw3, const float* __restrict__ ab3,
             const float* __restrict__ vw1, const float* __restrict__ vb1,
             const float* __restrict__ vw2, const float* __restrict__ vb2,
             const float* __restrict__ vw3, const float* __restrict__ vb3,
             const u16* __restrict__ ws,
             float* __restrict__ out_mean, float* __restrict__ out_val)
{
  __shared__ __align__(16) float sm[18816];
  float* sc   = sm;
  u16*   pAb  = (u16*)(sm + 8576);
  u16*   pAb2 = pAb + 8192;
  u16*   pAs  = (u16*)(sm + 16768);
  float* geb4 = sm + 16768;   // overlays As (dead after G1)
  float* geb  = sm + 17280;
  float* vh1  = sm + 17408;

  const int tid = threadIdx.x, b = blockIdx.x;
  const int wid = tid>>6, l15 = tid&15, g = (tid>>4)&3;

  // ---- P0: pack state -> As bf16 [64][64], XOR-swizzled, rows 50..63 zero ----
  {
    const float4* xb4 = (const float4*)(state + (size_t)b * (NNODE*64));
    for (int t = tid; t < 800; t += NT){
      float4 v = xb4[t];
      int i = t>>4, k0 = (t&15)*4;
      ushort4 u;
      u.x = f2bu(v.x); u.y = f2bu(v.y); u.z = f2bu(v.z); u.w = f2bu(v.w);
      *(ushort4*)(pAs + i*64 + (k0 ^ ((i&7)<<3))) = u;
    }
    for (int t = tid; t < 224; t += NT){
      int i = 50 + (t>>4), k0 = (t&15)*4;
      *(ushort4*)(pAs + i*64 + (k0 ^ ((i&7)<<3))) = (ushort4){0,0,0,0};
    }
  }
  __syncthreads();

  // ---- G1 + attention1, per head ----
  {
    s8v aS[4][2];
    #pragma unroll
    for (int mt=0;mt<4;++mt)
      #pragma unroll
      for (int ks=0;ks<2;++ks){
        int row = mt*16 + l15, c = ks*32 + g*8;
        aS[mt][ks] = *(const s8v*)(pAs + row*64 + (c ^ ((row&7)<<3)));
      }

    for (int h=0; h<2; ++h){
      // G1 head h: C[64][130] -> sc (cols 0..127 features, 128=es, 129=ed)
      for (int nt = wid; nt < 9; nt += 8){
        f4v acc[4];
        #pragma unroll
        for (int mt=0;mt<4;++mt) acc[mt] = (f4v){0.f,0.f,0.f,0.f};
        #pragma unroll
        for (int ks=0;ks<2;++ks){
          s8v bf = *(const s8v*)(ws + WS1 + h*9216 + (nt*16 + l15)*64 + ks*32 + g*8);
          #pragma unroll
          for (int mt=0;mt<4;++mt) acc[mt] = mfma16(aS[mt][ks], bf, acc[mt]);
        }
        const int col = nt*16 + l15;
        if (col < 130){
          #pragma unroll
          for (int mt=0;mt<4;++mt){
            const int r0 = mt*16 + g*4;
            #pragma unroll
            for (int r=0;r<4;++r) sc[(r0+r)*SCS + col] = acc[mt][r];
          }
        }
      }
      __syncthreads();

      // attention head h: 50x128 independent cells -> pack Abuf cols h*128..h*128+127
      {
        const int base_j = h*128;
        #pragma unroll 4
        for (int t=0; t<13; ++t){
          const int c = tid + t*NT;
          if (c < 6400){
            const int i = c >> 7, j = c & 127;
            const float edi = sc[i*SCS + 129];
            const float cur = sc[i*SCS + j];
            const float pv  = (i > 0)        ? sc[(i-1)*SCS + j] : 0.f;
            const float nx  = (i < NNODE-1)  ? sc[(i+1)*SCS + j] : 0.f;
            const float esf = lrelu(sc[i*SCS + 128] + edi, 0.2f);
            float m = esf, el = 0.f, er = 0.f;
            if (i > 0)       { el = lrelu(sc[(i-1)*SCS + 128] + edi, 0.2f); m = fmaxf(m, el); }
            if (i < NNODE-1) { er = lrelu(sc[(i+1)*SCS + 128] + edi, 0.2f); m = fmaxf(m, er); }
            const float wS = __expf(esf - m);
            const float wL = (i > 0)       ? __expf(el - m) : 0.f;
            const float wR = (i < NNODE-1) ? __expf(er - m) : 0.f;
            const float agg = (wL*pv + wS*cur + wR*nx) * fastrcp(wL+wS+wR);
            const float v = gelu_f(agg + b1[base_j + j]);
            const int jj = base_j + j;
            pAb[i*256 + (jj ^ ((i&7)<<3))] = f2bu(v);
          }
        }
      }
      __syncthreads();
    }
  }

  // ---- P3: G2  C[64][130] = A2[64x256] x W2x^T -> sc ----
  for (int nt = wid; nt < 9; nt += 8){
    f4v acc[4];
    #pragma unroll
    for (int mt=0;mt<4;++mt) acc[mt] = (f4v){0.f,0.f,0.f,0.f};
    #pragma unroll
    for (int ks=0;ks<8;++ks){
      s8v bf = *(const s8v*)(ws + WS2 + (nt*16 + l15)*256 + ks*32 + g*8);
      #pragma unroll
      for (int mt=0;mt<4;++mt){
        const int row = mt*16 + l15, c = ks*32 + g*8;
        s8v a = *(const s8v*)(pAb + row*256 + (c ^ ((row&7)<<3)));
        acc[mt] = mfma16(a, bf, acc[mt]);
      }
    }
    const int col = nt*16 + l15;
    if (col < 130){
      #pragma unroll
      for (int mt=0;mt<4;++mt){
        const int r0 = mt*16 + g*4;
        #pragma unroll
        for (int r=0;r<4;++r) sc[(r0+r)*SCS + col] = acc[mt][r];
      }
    }
  }
  __syncthreads();

  // ---- P4: attention2 + GELU -> A3 bf16 [64][128] ; pool partials (4 row-quarters) ----
  {
    const int q = tid>>7, j = tid&127;
    const int i0 = q*13, i1 = (i0+13 < NNODE) ? i0+13 : NNODE;
    const float bj = b2[j];
    float ps = 0.f;
    #pragma unroll 4
    for (int i = i0; i < i1; ++i){
      const float edi = sc[i*SCS + 129];
      const float cur = sc[i*SCS + j];
      const float pv  = (i > 0)       ? sc[(i-1)*SCS + j] : 0.f;
      const float nx  = (i < NNODE-1) ? sc[(i+1)*SCS + j] : 0.f;
      const float esf = lrelu(sc[i*SCS + 128] + edi, 0.2f);
      float m = esf, el = 0.f, er = 0.f;
      if (i > 0)       { el = lrelu(sc[(i-1)*SCS + 128] + edi, 0.2f); m = fmaxf(m, el); }
      if (i < NNODE-1) { er = lrelu(sc[(i+1)*SCS + 128] + edi, 0.2f); m = fmaxf(m, er); }
      const float wS = __expf(esf - m);
      const float wL = (i > 0)       ? __expf(el - m) : 0.f;
      const float wR = (i < NNODE-1) ? __expf(er - m) : 0.f;
      const float agg = (wL*pv + wS*cur + wR*nx) * fastrcp(wL+wS+wR);
      const float v = gelu_f(agg + bj);
      pAb[i*128 + (j ^ ((i&7)<<3))] = f2bu(v);
      ps += v;
    }
    geb4[q*128 + j] = ps;
  }
  __syncthreads();

  // ---- P5: G3  C = A3 x aw1^T ; fused lrelu+pack -> A4 (disjoint region) ; geb finalize ----
  {
    const int nt = wid;
    f4v acc[4];
    #pragma unroll
    for (int mt=0;mt<4;++mt) acc[mt] = (f4v){0.f,0.f,0.f,0.f};
    #pragma unroll
    for (int ks=0;ks<4;++ks){
      s8v bf = *(const s8v*)(ws + WSA1 + (nt*16 + l15)*128 + ks*32 + g*8);
      #pragma unroll
      for (int mt=0;mt<4;++mt){
        const int row = mt*16 + l15, c = ks*32 + g*8;
        s8v a = *(const s8v*)(pAb + row*128 + (c ^ ((row&7)<<3)));
        acc[mt] = mfma16(a, bf, acc[mt]);
      }
    }
    const int col = nt*16 + l15;
    const float bj = ab1[col];
    #pragma unroll
    for (int mt=0;mt<4;++mt){
      #pragma unroll
      for (int r=0;r<4;++r){
        const int row = mt*16 + g*4 + r;
        const float v = lrelu(acc[mt][r] + bj, 0.01f);
        pAb2[row*128 + (col ^ ((row&7)<<3))] = f2bu(v);
      }
    }
    if (tid < 128)
      geb[tid] = (geb4[tid] + geb4[128+tid] + geb4[256+tid] + geb4[384+tid]) * 0.02f;
  }
  __syncthreads();

  // ---- P7: G4  C = A4 x aw2^T -> sc ----
  {
    const int nt = wid;
    f4v acc[4];
    #pragma unroll
    for (int mt=0;mt<4;++mt) acc[mt] = (f4v){0.f,0.f,0.f,0.f};
    #pragma unroll
    for (int ks=0;ks<4;++ks){
      s8v bf = *(const s8v*)(ws + WSA2 + (nt*16 + l15)*128 + ks*32 + g*8);
      #pragma unroll
      for (int mt=0;mt<4;++mt){
        const int row = mt*16 + l15, c = ks*32 + g*8;
        s8v a = *(const s8v*)(pAb2 + row*128 + (c ^ ((row&7)<<3)));
        acc[mt] = mfma16(a, bf, acc[mt]);
      }
    }
    const int col = nt*16 + l15;
    #pragma unroll
    for (int mt=0;mt<4;++mt){
      const int r0 = mt*16 + g*4;
      #pragma unroll
      for (int r=0;r<4;++r) sc[(r0+r)*SCS + col] = acc[mt][r];
    }
  }
  __syncthreads();

  // ---- P8: actor L3 -> out_mean ; value L1 -> vh1 ----
  if (tid < 200){
    const int i = tid>>2, m = tid&3;
    const float* scr = sc + i*SCS;
    float s0=0.f,s1=0.f,s2=0.f,s3=0.f;
    #pragma unroll 4
    for (int k=0;k<128;k+=4){
      s0 += lrelu(scr[k  ]+ab2[k  ],0.01f)*aw3[(k  )*4+m];
      s1 += lrelu(scr[k+1]+ab2[k+1],0.01f)*aw3[(k+1)*4+m];
      s2 += lrelu(scr[k+2]+ab2[k+2],0.01f)*aw3[(k+2)*4+m];
      s3 += lrelu(scr[k+3]+ab2[k+3],0.01f)*aw3[(k+3)*4+m];
    }
    out_mean[(size_t)b*200 + i*4 + m] = (s0+s1)+(s2+s3) + ab3[m];
  } else if (tid >= 256 && tid < 384){
    const int j = tid - 256;
    float a0=0.f, a1=0.f;
    #pragma unroll 4
    for (int k=0;k<128;k+=2){
      a0 += geb[k  ]*vw1[(k  )*128 + j];
      a1 += geb[k+1]*vw1[(k+1)*128 + j];
    }
    vh1[j] = lrelu(a0+a1 + vb1[j], 0.01f);
  }
  __syncthreads();

  // ---- tail (wave 0 only, no more barriers): value L2 + head ----
  if (tid < 64){
    const int j = tid;
    float a0=0.f, c0=0.f;
    #pragma unroll 4
    for (int k=0;k<128;++k){
      const float gk = vh1[k];
      a0 += gk*vw2[k*128 + j];
      c0 += gk*vw2[k*128 + j + 64];
    }
    const float va = lrelu(a0 + vb2[j],    0.01f);
    const float vb = lrelu(c0 + vb2[j+64], 0.01f);
    float p = va*vw3[j] + vb*vw3[j+64];
    #pragma unroll
    for (int off=32; off>0; off>>=1) p += __shfl_down(p, off);
    if (j == 0) out_val[b] = p + vb3[0];
  }
}

extern "C" void kernel_launch(void* const* d_in, const int* in_sizes, int n_in,
                              void* d_out, int out_size, void* d_ws, size_t ws_size,
                              hipStream_t stream)
{
  const float* state = (const float*)d_in[0];
  const float* w1    = (const float*)d_in[1];
  const float* as1   = (const float*)d_in[2];
  const float* ad1   = (const float*)d_in[3];
  const float* b1_   = (const float*)d_in[4];
  const float* w2    = (const float*)d_in[5];
  const float* as2   = (const float*)d_in[6];
  const float* ad2   = (const float*)d_in[7];
  const float* b2_   = (const float*)d_in[8];
  const float* aw1   = (const float*)d_in[9];
  const float* ab1   = (const float*)d_in[10];
  const float* aw2   = (const float*)d_in[11];
  const float* ab2   = (const float*)d_in[12];
  const float* aw3   = (const float*)d_in[13];
  const float* ab3   = (const float*)d_in[14];
  const float* vw1   = (const float*)d_in[15];
  const float* vb1   = (const float*)d_in[16];
  const float* vw2   = (const float*)d_in[17];
  const float* vb2   = (const float*)d_in[18];
  const float* vw3   = (const float*)d_in[19];
  const float* vb3   = (const float*)d_in[20];

  const int B = in_sizes[0] / (NNODE * 64);   // 2048
  float* out_mean = (float*)d_out;
  float* out_val  = out_mean + (size_t)B * 200;
  u16* ws = (u16*)d_ws;

  ac_prep<<<128, 256, 0, stream>>>(w1, as1, ad1, w2, as2, ad2, aw1, aw2, ws);
  ac_main<<<B, NT, 0, stream>>>(state, b1_, b2_, ab1, ab2, aw3, ab3,
                                vw1, vb1, vw2, vb2, vw3, vb3,
                                ws, out_mean, out_val);
}